// Round 7
// baseline (333.276 us; speedup 1.0000x reference)
//
#include <hip/hip_runtime.h>

// GCN 3-layer forward on MI355X.
// CSR build (by dst): count+slot pass using per-XCD private counter copies
// (selected via HW_REG_XCC_ID) and workgroup-scope atomics so the RMW executes
// in the local TCC (L2) instead of bypassing to the memory-side coherence
// point. reduce8 folds the 8 copies into degrees/offsets/norms; hierarchical
// scan -> row_ptr; atomic-free scatter (+ fused bf16 convert).
// Per layer:
//   xb[u] = bf16(norm_src[u] * x[u])          (pre-scaled bf16 node table)
//   agg[v] = sum_{u->v} xb[u]                 (pure bf16 gather-sum, fp32 accum)
//   h' = bf16( ns * relu(nd * agg @ W + b) )  (next layer's pre-scaled table)
// Layer 3: y = h2' @ W3 (fp32), then 40-dim agg with nd + b3.

#define SCAN_CHUNK 4096
#define NXCD 8

__device__ __forceinline__ ushort f2bf(float f) {
    unsigned u = __float_as_uint(f);
    unsigned r = (u + 0x7fffu + ((u >> 16) & 1u)) >> 16;  // RN-even
    return (ushort)r;
}
__device__ __forceinline__ void unpack2(unsigned w, float& lo, float& hi) {
    lo = __uint_as_float(w << 16);
    hi = __uint_as_float(w & 0xffff0000u);
}
__device__ __forceinline__ unsigned xcc_id() {
    unsigned x;
    asm volatile("s_getreg_b32 %0, hwreg(HW_REG_XCC_ID)" : "=s"(x));
    return x & (NXCD - 1);
}

// Histogram + slot assignment into per-XCD private copies; workgroup-scope
// atomics execute in the local TCC (no device-scope memory-side bypass).
// tmp_slot[e] = (xcd << 24) | within-(xcd,dst) slot.
__global__ __launch_bounds__(256) void count_slot_kernel(const int* __restrict__ ei, int E,
        int n, int* __restrict__ cnt_src, int* __restrict__ cnt_dst,
        int* __restrict__ tmp_slot) {
    int e = blockIdx.x * 256 + threadIdx.x;
    if (e >= E) return;
    unsigned xcd = xcc_id();
    int s = ei[e];
    int d = ei[E + e];
    __hip_atomic_fetch_add(&cnt_src[xcd * n + s], 1, __ATOMIC_RELAXED,
                           __HIP_MEMORY_SCOPE_WORKGROUP);
    int slot = __hip_atomic_fetch_add(&cnt_dst[xcd * n + d], 1, __ATOMIC_RELAXED,
                                      __HIP_MEMORY_SCOPE_WORKGROUP);
    tmp_slot[e] = (int)((xcd << 24) | (unsigned)slot);
}

// Fold 8 copies: deg_in (for scan), per-copy exclusive offsets, norms.
__global__ __launch_bounds__(256) void reduce8_kernel(const int* __restrict__ cnt_src,
        const int* __restrict__ cnt_dst, int n, int* __restrict__ deg_in,
        int* __restrict__ off8, float* __restrict__ norm_src, float* __restrict__ norm_dst) {
    int v = blockIdx.x * 256 + threadIdx.x;
    if (v >= n) return;
    int run = 0;
    #pragma unroll
    for (int c = 0; c < NXCD; ++c) {
        off8[c * n + v] = run;
        run += cnt_dst[c * n + v];
    }
    deg_in[v] = run;
    int so = 0;
    #pragma unroll
    for (int c = 0; c < NXCD; ++c) so += cnt_src[c * n + v];
    norm_dst[v] = rsqrtf((float)(run > 0 ? run : 1));
    norm_src[v] = rsqrtf((float)(so > 0 ? so : 1));
}

__global__ __launch_bounds__(256) void scan_blocksum(const int* __restrict__ deg_in, int n,
                                                     int* __restrict__ partials) {
    __shared__ int red[256];
    int t = threadIdx.x;
    int base = blockIdx.x * SCAN_CHUNK;
    int s = 0;
    for (int i = t; i < SCAN_CHUNK; i += 256) {
        int idx = base + i;
        if (idx < n) s += deg_in[idx];
    }
    red[t] = s;
    __syncthreads();
    for (int off = 128; off > 0; off >>= 1) {
        if (t < off) red[t] += red[t + off];
        __syncthreads();
    }
    if (t == 0) partials[blockIdx.x] = red[0];
}

__global__ __launch_bounds__(256) void scan_partials(int* __restrict__ partials, int nparts,
                                                     int* __restrict__ row_ptr, int n) {
    __shared__ int s[256];
    int t = threadIdx.x;
    s[t] = (t < nparts) ? partials[t] : 0;
    __syncthreads();
    for (int off = 1; off < 256; off <<= 1) {
        int v = (t >= off) ? s[t - off] : 0;
        __syncthreads();
        s[t] += v;
        __syncthreads();
    }
    int incl = s[t];
    int excl = incl - ((t < nparts) ? partials[t] : 0);
    if (t < nparts) partials[t] = excl;
    if (t == 255) row_ptr[n] = incl;
}

// Per-chunk exclusive scan -> row_ptr.
__global__ __launch_bounds__(256) void scan_emit(const int* __restrict__ deg_in,
                                                 const int* __restrict__ partials, int n,
                                                 int* __restrict__ row_ptr) {
    __shared__ int tsum[256];
    int t = threadIdx.x;
    int base = blockIdx.x * SCAN_CHUNK + t * 16;
    int local[16];
    int s = 0;
    #pragma unroll
    for (int i = 0; i < 16; ++i) {
        int idx = base + i;
        int v = (idx < n) ? deg_in[idx] : 0;
        local[i] = v;
        s += v;
    }
    tsum[t] = s;
    __syncthreads();
    for (int off = 1; off < 256; off <<= 1) {
        int v = (t >= off) ? tsum[t - off] : 0;
        __syncthreads();
        tsum[t] += v;
        __syncthreads();
    }
    int run = partials[blockIdx.x] + (t ? tsum[t - 1] : 0);
    #pragma unroll
    for (int i = 0; i < 16; ++i) {
        int idx = base + i;
        if (idx < n) {
            row_ptr[idx] = run;
            run += local[i];
        }
    }
}

// Fused heterogeneous dispatch: blocks [0, eb) scatter CSR cols (atomic-free),
// blocks [eb, eb+cb) convert features to pre-scaled bf16.
__global__ __launch_bounds__(256) void scatter_convert_kernel(const int* __restrict__ ei, int E,
        int n, const int* __restrict__ row_ptr, const int* __restrict__ tmp_slot,
        const int* __restrict__ off8, int* __restrict__ col, int eb,
        const float* __restrict__ x, const float* __restrict__ ns,
        ushort* __restrict__ xb) {
    if ((int)blockIdx.x < eb) {
        int e = blockIdx.x * 256 + threadIdx.x;
        if (e < E) {
            int s = ei[e];
            int d = ei[E + e];
            int ts = tmp_slot[e];
            unsigned copy = ((unsigned)ts) >> 24;
            int slot = ts & 0xFFFFFF;
            col[row_ptr[d] + off8[copy * n + d] + slot] = s;
        }
    } else {
        int i = (blockIdx.x - eb) * 256 + threadIdx.x;
        if (i < n * 32) {
            int row = i >> 5;
            float s = ns[row];
            float4 v = reinterpret_cast<const float4*>(x)[i];
            ushort4 o;
            o.x = f2bf(v.x * s); o.y = f2bf(v.y * s);
            o.z = f2bf(v.z * s); o.w = f2bf(v.w * s);
            reinterpret_cast<ushort4*>(xb)[i] = o;
        }
    }
}

// One wave per node: out[v][:] = sum_{u->v} xb[u][:] (bf16 rows, fp32 accum).
// 4 edges per iteration: 16 lanes x 8 dims each (16B loads); quarter-wave combine at end.
__global__ __launch_bounds__(256) void agg128_kernel(const ushort* __restrict__ xb,
        const int* __restrict__ row_ptr, const int* __restrict__ col,
        float* __restrict__ out, int n) {
    int wid  = (blockIdx.x * blockDim.x + threadIdx.x) >> 6;
    int lane = threadIdx.x & 63;
    if (wid >= n) return;
    int start = row_ptr[wid], end = row_ptr[wid + 1];
    int quarter = lane >> 4, l4 = lane & 15;
    float acc[8];
    #pragma unroll
    for (int i = 0; i < 8; ++i) acc[i] = 0.f;
    for (int b = start; b < end; b += 64) {
        int m = end - b; if (m > 64) m = 64;
        int u = 0;
        if (lane < m) u = col[b + lane];
        for (int j = 0; j < m; j += 4) {
            int jj = j + quarter;
            int uu = __shfl(u, jj);
            if (jj < m) {
                const uint4 v = *reinterpret_cast<const uint4*>(xb + (size_t)uu * 128 + 8 * l4);
                float f0, f1;
                unpack2(v.x, f0, f1); acc[0] += f0; acc[1] += f1;
                unpack2(v.y, f0, f1); acc[2] += f0; acc[3] += f1;
                unpack2(v.z, f0, f1); acc[4] += f0; acc[5] += f1;
                unpack2(v.w, f0, f1); acc[6] += f0; acc[7] += f1;
            }
        }
    }
    #pragma unroll
    for (int i = 0; i < 8; ++i) {
        acc[i] += __shfl_xor(acc[i], 16);
        acc[i] += __shfl_xor(acc[i], 32);
    }
    if (lane < 16) {
        float* op = out + (size_t)wid * 128 + 8 * lane;
        *reinterpret_cast<float4*>(op)     = make_float4(acc[0], acc[1], acc[2], acc[3]);
        *reinterpret_cast<float4*>(op + 4) = make_float4(acc[4], acc[5], acc[6], acc[7]);
    }
}

// out[r][:] = bf16( ns[r] * relu( nd[r] * (xin[r][:] @ W) + b ) ), W 128x128 row-major.
// 32 rows/block (16KB LDS); W streamed from L2. Wave w -> rows w*8..+7, lane -> cols lane,lane+64.
__global__ __launch_bounds__(256, 4) void mm128_kernel(const float* __restrict__ xin,
        const float* __restrict__ W, const float* __restrict__ bias,
        const float* __restrict__ norm_dst, const float* __restrict__ norm_src,
        ushort* __restrict__ out, int n) {
    __shared__ float Xl[32][128];
    int t = threadIdx.x;
    int row0 = blockIdx.x * 32;
    for (int i = t; i < 32 * 32; i += 256) {
        int r = i >> 5, k4 = i & 31;
        int gr = row0 + r;
        float4 xv = make_float4(0.f, 0.f, 0.f, 0.f);
        if (gr < n) xv = reinterpret_cast<const float4*>(xin)[(size_t)gr * 32 + k4];
        reinterpret_cast<float4*>(&Xl[r][0])[k4] = xv;
    }
    __syncthreads();
    int wv = t >> 6, lane = t & 63;
    int c0 = lane, c1 = lane + 64;
    float acc0[8], acc1[8];
    #pragma unroll
    for (int r = 0; r < 8; ++r) { acc0[r] = 0.f; acc1[r] = 0.f; }
    int rbase = wv * 8;
    const float* Wp0 = W + c0;
    const float* Wp1 = W + c1;
    for (int k = 0; k < 128; k += 4) {
        float w00 = Wp0[(k + 0) * 128], w10 = Wp1[(k + 0) * 128];
        float w01 = Wp0[(k + 1) * 128], w11 = Wp1[(k + 1) * 128];
        float w02 = Wp0[(k + 2) * 128], w12 = Wp1[(k + 2) * 128];
        float w03 = Wp0[(k + 3) * 128], w13 = Wp1[(k + 3) * 128];
        #pragma unroll
        for (int r = 0; r < 8; ++r) {
            float4 xv = *reinterpret_cast<const float4*>(&Xl[rbase + r][k]);
            acc0[r] = fmaf(xv.x, w00, acc0[r]);
            acc1[r] = fmaf(xv.x, w10, acc1[r]);
            acc0[r] = fmaf(xv.y, w01, acc0[r]);
            acc1[r] = fmaf(xv.y, w11, acc1[r]);
            acc0[r] = fmaf(xv.z, w02, acc0[r]);
            acc1[r] = fmaf(xv.z, w12, acc1[r]);
            acc0[r] = fmaf(xv.w, w03, acc0[r]);
            acc1[r] = fmaf(xv.w, w13, acc1[r]);
        }
    }
    float b0 = bias[c0], b1 = bias[c1];
    #pragma unroll
    for (int r = 0; r < 8; ++r) {
        int gr = row0 + rbase + r;
        if (gr < n) {
            float nd = norm_dst[gr], ns = norm_src[gr];
            float v0 = fmaxf(fmaf(nd, acc0[r], b0), 0.f) * ns;
            float v1 = fmaxf(fmaf(nd, acc1[r], b1), 0.f) * ns;
            out[(size_t)gr * 128 + c0] = f2bf(v0);
            out[(size_t)gr * 128 + c1] = f2bf(v1);
        }
    }
}

// y[r][c] = xin_bf16[r][:] @ W3[:,c], c < 40 (input already ns-prescaled). fp32 out.
__global__ __launch_bounds__(256, 4) void mm40_kernel(const ushort* __restrict__ xin,
        const float* __restrict__ W, float* __restrict__ out, int n) {
    __shared__ float Xl[32][128];
    int t = threadIdx.x;
    int row0 = blockIdx.x * 32;
    for (int i = t; i < 512; i += 256) {
        int r = i >> 4, c8 = i & 15;
        int gr = row0 + r;
        float4 a0 = make_float4(0.f, 0.f, 0.f, 0.f);
        float4 a1 = make_float4(0.f, 0.f, 0.f, 0.f);
        if (gr < n) {
            uint4 v = *reinterpret_cast<const uint4*>(xin + (size_t)gr * 128 + 8 * c8);
            unpack2(v.x, a0.x, a0.y); unpack2(v.y, a0.z, a0.w);
            unpack2(v.z, a1.x, a1.y); unpack2(v.w, a1.z, a1.w);
        }
        float4* lp = reinterpret_cast<float4*>(&Xl[r][8 * c8]);
        lp[0] = a0; lp[1] = a1;
    }
    __syncthreads();
    int wv = t >> 6, lane = t & 63;
    int c = (lane < 40) ? lane : 0;
    float acc[8];
    #pragma unroll
    for (int r = 0; r < 8; ++r) acc[r] = 0.f;
    int rbase = wv * 8;
    const float* Wp = W + c;
    for (int k = 0; k < 128; k += 2) {
        float w0 = Wp[(k + 0) * 40];
        float w1 = Wp[(k + 1) * 40];
        #pragma unroll
        for (int r = 0; r < 8; ++r) {
            float2 xv = *reinterpret_cast<const float2*>(&Xl[rbase + r][k]);
            acc[r] = fmaf(xv.x, w0, acc[r]);
            acc[r] = fmaf(xv.y, w1, acc[r]);
        }
    }
    if (lane < 40) {
        #pragma unroll
        for (int r = 0; r < 8; ++r) {
            int gr = row0 + rbase + r;
            if (gr < n) out[(size_t)gr * 40 + lane] = acc[r];
        }
    }
}

// out[v][c] = norm_dst[v] * sum_{u->v} y[u][c] + b3[c], c < 40. One wave/node.
__global__ __launch_bounds__(256) void agg40_kernel(const float* __restrict__ y,
        const int* __restrict__ row_ptr, const int* __restrict__ col,
        const float* __restrict__ norm_dst, const float* __restrict__ b3,
        float* __restrict__ out, int n) {
    int wid  = (blockIdx.x * blockDim.x + threadIdx.x) >> 6;
    int lane = threadIdx.x & 63;
    if (wid >= n) return;
    int start = row_ptr[wid], end = row_ptr[wid + 1];
    float acc = 0.f;
    for (int b = start; b < end; b += 64) {
        int m = end - b; if (m > 64) m = 64;
        int u = 0;
        if (lane < m) u = col[b + lane];
        for (int j = 0; j < m; ++j) {
            int uu = __shfl(u, j);
            if (lane < 40) acc += y[(size_t)uu * 40 + lane];
        }
    }
    if (lane < 40) out[(size_t)wid * 40 + lane] = norm_dst[wid] * acc + b3[lane];
}

extern "C" void kernel_launch(void* const* d_in, const int* in_sizes, int n_in,
                              void* d_out, int out_size, void* d_ws, size_t ws_size,
                              hipStream_t stream) {
    const float* features = (const float*)d_in[0];
    const int*   ei       = (const int*)d_in[1];
    const float* W1 = (const float*)d_in[2];
    const float* b1 = (const float*)d_in[3];
    const float* W2 = (const float*)d_in[4];
    const float* b2 = (const float*)d_in[5];
    const float* W3 = (const float*)d_in[6];
    const float* b3 = (const float*)d_in[7];

    const int n = in_sizes[0] / 128;
    const int E = in_sizes[1] / 2;

    char* w = (char*)d_ws;
    auto alloc = [&](size_t bytes) {
        char* p = w;
        w += (bytes + 255) & ~(size_t)255;
        return p;
    };
    int*    cnt      = (int*)   alloc((size_t)2 * NXCD * n * 4);  // cnt_src[8][n] | cnt_dst[8][n]
    int*    off8     = (int*)   alloc((size_t)NXCD * n * 4);
    int*    deg_in   = (int*)   alloc((size_t)n * 4);
    float*  norm_src = (float*) alloc((size_t)n * 4);
    float*  norm_dst = (float*) alloc((size_t)n * 4);
    int*    row_ptr  = (int*)   alloc((size_t)(n + 1) * 4);
    int*    partials = (int*)   alloc((size_t)256 * 4);
    int*    tmp_slot = (int*)   alloc((size_t)E * 4);
    int*    col      = (int*)   alloc((size_t)E * 4);
    ushort* xb       = (ushort*)alloc((size_t)n * 128 * 2);  // bf16 node table (reused per layer)
    float*  bufA     = (float*) alloc((size_t)n * 128 * 4);  // fp32 agg / y buffer

    int* cnt_src = cnt;
    int* cnt_dst = cnt + NXCD * n;

    hipMemsetAsync(cnt, 0, (size_t)2 * NXCD * n * 4, stream);

    int eb = (E + 255) / 256;            // 1 edge per thread
    int nb = (n + 255) / 256;
    int sb = (n + SCAN_CHUNK - 1) / SCAN_CHUNK;
    int cb = (n * 32 + 255) / 256;       // convert blocks

    count_slot_kernel<<<eb, 256, 0, stream>>>(ei, E, n, cnt_src, cnt_dst, tmp_slot);
    reduce8_kernel<<<nb, 256, 0, stream>>>(cnt_src, cnt_dst, n, deg_in, off8,
                                           norm_src, norm_dst);
    scan_blocksum<<<sb, 256, 0, stream>>>(deg_in, n, partials);
    scan_partials<<<1, 256, 0, stream>>>(partials, sb, row_ptr, n);
    scan_emit<<<sb, 256, 0, stream>>>(deg_in, partials, n, row_ptr);
    scatter_convert_kernel<<<eb + cb, 256, 0, stream>>>(ei, E, n, row_ptr, tmp_slot,
                                                        off8, col, eb,
                                                        features, norm_src, xb);

    int ab = (n + 3) / 4;
    int mb = (n + 31) / 32;

    agg128_kernel<<<ab, 256, 0, stream>>>(xb, row_ptr, col, bufA, n);
    mm128_kernel<<<mb, 256, 0, stream>>>(bufA, W1, b1, norm_dst, norm_src, xb, n);
    agg128_kernel<<<ab, 256, 0, stream>>>(xb, row_ptr, col, bufA, n);
    mm128_kernel<<<mb, 256, 0, stream>>>(bufA, W2, b2, norm_dst, norm_src, xb, n);
    mm40_kernel<<<mb, 256, 0, stream>>>(xb, W3, bufA, n);
    agg40_kernel<<<ab, 256, 0, stream>>>(bufA, row_ptr, col, norm_dst, b3, (float*)d_out, n);
}

// Round 8
// 319.212 us; speedup vs baseline: 1.0441x; 1.0441x over previous
//
#include <hip/hip_runtime.h>

// GCN 3-layer forward on MI355X.
// Key identity: segment_sum(M) @ W == segment_sum(M @ W), so each layer's
// matmul can run BEFORE aggregation. Layer 1's mm depends only on inputs ->
// fused into the CSR-build count dispatch (atomic-bound, machine idle).
// Pipeline:
//   [mm1 || count+slot]  T1 = x@W1 hidden under the ~75us atomic floor
//   scan -> row_ptr, norms
//   [scatter || convert] col placement + xb1 = bf16(ns*T1)
//   agg128 (bf16 gather-sum) -> agg1
//   mm128_l2: X' = relu(nd*agg1+b1) @ W2, out bf16(ns*.) -> xb2
//   agg128 -> agg2
//   mm40_l3: X'' = ns*relu(nd*agg2+b2) @ W3 -> y fp32
//   agg40: nd * sum y + b3 -> out

#define SCAN_CHUNK 4096

__device__ __forceinline__ ushort f2bf(float f) {
    unsigned u = __float_as_uint(f);
    unsigned r = (u + 0x7fffu + ((u >> 16) & 1u)) >> 16;  // RN-even
    return (ushort)r;
}
__device__ __forceinline__ void unpack2(unsigned w, float& lo, float& hi) {
    lo = __uint_as_float(w << 16);
    hi = __uint_as_float(w & 0xffff0000u);
}

// Heterogeneous dispatch: blocks [0,mb) compute T1 = x@W1 (raw fp32, 32-row
// tiles); blocks [mb,mb+eb) do the CSR count+slot atomic pass. The VALU-bound
// mm fills CUs while the atomic pass waits on the memory-side RMW engine.
__global__ __launch_bounds__(256, 4) void mm1_count_kernel(
        const float* __restrict__ x, const float* __restrict__ W1,
        float* __restrict__ T1, int n, int mb,
        const int* __restrict__ ei, int E,
        int* __restrict__ cnt_src, int* __restrict__ cnt_dst,
        int* __restrict__ tmp_slot) {
    if ((int)blockIdx.x >= mb) {
        int e = ((int)blockIdx.x - mb) * 256 + threadIdx.x;
        if (e < E) {
            int s = ei[e];
            int d = ei[E + e];
            atomicAdd(&cnt_src[s], 1);
            tmp_slot[e] = atomicAdd(&cnt_dst[d], 1);
        }
        return;
    }
    __shared__ float Xl[32][128];
    int t = threadIdx.x;
    int row0 = blockIdx.x * 32;
    for (int i = t; i < 32 * 32; i += 256) {
        int r = i >> 5, k4 = i & 31;
        int gr = row0 + r;
        float4 xv = make_float4(0.f, 0.f, 0.f, 0.f);
        if (gr < n) xv = reinterpret_cast<const float4*>(x)[(size_t)gr * 32 + k4];
        reinterpret_cast<float4*>(&Xl[r][0])[k4] = xv;
    }
    __syncthreads();
    int wv = t >> 6, lane = t & 63;
    int c0 = lane, c1 = lane + 64;
    float acc0[8], acc1[8];
    #pragma unroll
    for (int r = 0; r < 8; ++r) { acc0[r] = 0.f; acc1[r] = 0.f; }
    int rbase = wv * 8;
    const float* Wp0 = W1 + c0;
    const float* Wp1 = W1 + c1;
    for (int k = 0; k < 128; k += 4) {
        float w00 = Wp0[(k + 0) * 128], w10 = Wp1[(k + 0) * 128];
        float w01 = Wp0[(k + 1) * 128], w11 = Wp1[(k + 1) * 128];
        float w02 = Wp0[(k + 2) * 128], w12 = Wp1[(k + 2) * 128];
        float w03 = Wp0[(k + 3) * 128], w13 = Wp1[(k + 3) * 128];
        #pragma unroll
        for (int r = 0; r < 8; ++r) {
            float4 xv = *reinterpret_cast<const float4*>(&Xl[rbase + r][k]);
            acc0[r] = fmaf(xv.x, w00, acc0[r]);
            acc1[r] = fmaf(xv.x, w10, acc1[r]);
            acc0[r] = fmaf(xv.y, w01, acc0[r]);
            acc1[r] = fmaf(xv.y, w11, acc1[r]);
            acc0[r] = fmaf(xv.z, w02, acc0[r]);
            acc1[r] = fmaf(xv.z, w12, acc1[r]);
            acc0[r] = fmaf(xv.w, w03, acc0[r]);
            acc1[r] = fmaf(xv.w, w13, acc1[r]);
        }
    }
    #pragma unroll
    for (int r = 0; r < 8; ++r) {
        int gr = row0 + rbase + r;
        if (gr < n) {
            T1[(size_t)gr * 128 + c0] = acc0[r];
            T1[(size_t)gr * 128 + c1] = acc1[r];
        }
    }
}

__global__ __launch_bounds__(256) void scan_blocksum(const int* __restrict__ deg_in, int n,
                                                     int* __restrict__ partials) {
    __shared__ int red[256];
    int t = threadIdx.x;
    int base = blockIdx.x * SCAN_CHUNK;
    int s = 0;
    for (int i = t; i < SCAN_CHUNK; i += 256) {
        int idx = base + i;
        if (idx < n) s += deg_in[idx];
    }
    red[t] = s;
    __syncthreads();
    for (int off = 128; off > 0; off >>= 1) {
        if (t < off) red[t] += red[t + off];
        __syncthreads();
    }
    if (t == 0) partials[blockIdx.x] = red[0];
}

__global__ __launch_bounds__(256) void scan_partials(int* __restrict__ partials, int nparts,
                                                     int* __restrict__ row_ptr, int n) {
    __shared__ int s[256];
    int t = threadIdx.x;
    s[t] = (t < nparts) ? partials[t] : 0;
    __syncthreads();
    for (int off = 1; off < 256; off <<= 1) {
        int v = (t >= off) ? s[t - off] : 0;
        __syncthreads();
        s[t] += v;
        __syncthreads();
    }
    int incl = s[t];
    int excl = incl - ((t < nparts) ? partials[t] : 0);
    if (t < nparts) partials[t] = excl;
    if (t == 255) row_ptr[n] = incl;
}

// Per-chunk exclusive scan -> row_ptr, fused norm compute.
__global__ __launch_bounds__(256) void scan_emit(const int* __restrict__ deg_in,
                                                 const int* __restrict__ deg_out,
                                                 const int* __restrict__ partials, int n,
                                                 int* __restrict__ row_ptr,
                                                 float* __restrict__ norm_src,
                                                 float* __restrict__ norm_dst) {
    __shared__ int tsum[256];
    int t = threadIdx.x;
    int base = blockIdx.x * SCAN_CHUNK + t * 16;
    int local[16];
    int s = 0;
    #pragma unroll
    for (int i = 0; i < 16; ++i) {
        int idx = base + i;
        int v = (idx < n) ? deg_in[idx] : 0;
        local[i] = v;
        s += v;
    }
    tsum[t] = s;
    __syncthreads();
    for (int off = 1; off < 256; off <<= 1) {
        int v = (t >= off) ? tsum[t - off] : 0;
        __syncthreads();
        tsum[t] += v;
        __syncthreads();
    }
    int run = partials[blockIdx.x] + (t ? tsum[t - 1] : 0);
    #pragma unroll
    for (int i = 0; i < 16; ++i) {
        int idx = base + i;
        if (idx < n) {
            row_ptr[idx] = run;
            run += local[i];
            int di = local[i] > 0 ? local[i] : 1;
            int dq = deg_out[idx] > 0 ? deg_out[idx] : 1;
            norm_dst[idx] = rsqrtf((float)di);
            norm_src[idx] = rsqrtf((float)dq);
        }
    }
}

// Heterogeneous: blocks [0,eb) scatter CSR cols (atomic-free); blocks
// [eb,eb+cb) convert T1 to pre-scaled bf16 table xb = bf16(ns*T1).
__global__ __launch_bounds__(256) void scatter_convert_kernel(const int* __restrict__ ei, int E,
        const int* __restrict__ row_ptr, const int* __restrict__ tmp_slot,
        int* __restrict__ col, int eb,
        const float* __restrict__ T1, const float* __restrict__ ns,
        ushort* __restrict__ xb, int n) {
    if ((int)blockIdx.x < eb) {
        int e = blockIdx.x * 256 + threadIdx.x;
        if (e < E) {
            int s = ei[e];
            int d = ei[E + e];
            col[row_ptr[d] + tmp_slot[e]] = s;
        }
    } else {
        int i = ((int)blockIdx.x - eb) * 256 + threadIdx.x;
        if (i < n * 32) {
            int row = i >> 5;
            float s = ns[row];
            float4 v = reinterpret_cast<const float4*>(T1)[i];
            ushort4 o;
            o.x = f2bf(v.x * s); o.y = f2bf(v.y * s);
            o.z = f2bf(v.z * s); o.w = f2bf(v.w * s);
            reinterpret_cast<ushort4*>(xb)[i] = o;
        }
    }
}

// One wave per node: out[v][:] = sum_{u->v} xb[u][:] (bf16 rows, fp32 accum).
// 4 edges per iteration: 16 lanes x 8 dims each (16B loads); quarter-wave combine at end.
__global__ __launch_bounds__(256) void agg128_kernel(const ushort* __restrict__ xb,
        const int* __restrict__ row_ptr, const int* __restrict__ col,
        float* __restrict__ out, int n) {
    int wid  = (blockIdx.x * blockDim.x + threadIdx.x) >> 6;
    int lane = threadIdx.x & 63;
    if (wid >= n) return;
    int start = row_ptr[wid], end = row_ptr[wid + 1];
    int quarter = lane >> 4, l4 = lane & 15;
    float acc[8];
    #pragma unroll
    for (int i = 0; i < 8; ++i) acc[i] = 0.f;
    for (int b = start; b < end; b += 64) {
        int m = end - b; if (m > 64) m = 64;
        int u = 0;
        if (lane < m) u = col[b + lane];
        for (int j = 0; j < m; j += 4) {
            int jj = j + quarter;
            int uu = __shfl(u, jj);
            if (jj < m) {
                const uint4 v = *reinterpret_cast<const uint4*>(xb + (size_t)uu * 128 + 8 * l4);
                float f0, f1;
                unpack2(v.x, f0, f1); acc[0] += f0; acc[1] += f1;
                unpack2(v.y, f0, f1); acc[2] += f0; acc[3] += f1;
                unpack2(v.z, f0, f1); acc[4] += f0; acc[5] += f1;
                unpack2(v.w, f0, f1); acc[6] += f0; acc[7] += f1;
            }
        }
    }
    #pragma unroll
    for (int i = 0; i < 8; ++i) {
        acc[i] += __shfl_xor(acc[i], 16);
        acc[i] += __shfl_xor(acc[i], 32);
    }
    if (lane < 16) {
        float* op = out + (size_t)wid * 128 + 8 * lane;
        *reinterpret_cast<float4*>(op)     = make_float4(acc[0], acc[1], acc[2], acc[3]);
        *reinterpret_cast<float4*>(op + 4) = make_float4(acc[4], acc[5], acc[6], acc[7]);
    }
}

// Layer 2: X' = relu(nd*agg1 + b1) applied at LDS-load; acc = X'@W2;
// epilogue writes xb2 = bf16(ns*acc). 32-row tiles; W2 streamed from L2.
__global__ __launch_bounds__(256, 4) void mm128_l2_kernel(const float* __restrict__ agg,
        const float* __restrict__ W2, const float* __restrict__ b1,
        const float* __restrict__ norm_dst, const float* __restrict__ norm_src,
        ushort* __restrict__ out, int n) {
    __shared__ float Xl[32][128];
    int t = threadIdx.x;
    int row0 = blockIdx.x * 32;
    for (int i = t; i < 32 * 32; i += 256) {
        int r = i >> 5, k4 = i & 31;
        int gr = row0 + r;
        float4 xv = make_float4(0.f, 0.f, 0.f, 0.f);
        if (gr < n) {
            xv = reinterpret_cast<const float4*>(agg)[(size_t)gr * 32 + k4];
            float4 bb = reinterpret_cast<const float4*>(b1)[k4];
            float nd = norm_dst[gr];
            xv.x = fmaxf(fmaf(nd, xv.x, bb.x), 0.f);
            xv.y = fmaxf(fmaf(nd, xv.y, bb.y), 0.f);
            xv.z = fmaxf(fmaf(nd, xv.z, bb.z), 0.f);
            xv.w = fmaxf(fmaf(nd, xv.w, bb.w), 0.f);
        }
        reinterpret_cast<float4*>(&Xl[r][0])[k4] = xv;
    }
    __syncthreads();
    int wv = t >> 6, lane = t & 63;
    int c0 = lane, c1 = lane + 64;
    float acc0[8], acc1[8];
    #pragma unroll
    for (int r = 0; r < 8; ++r) { acc0[r] = 0.f; acc1[r] = 0.f; }
    int rbase = wv * 8;
    const float* Wp0 = W2 + c0;
    const float* Wp1 = W2 + c1;
    for (int k = 0; k < 128; k += 4) {
        float w00 = Wp0[(k + 0) * 128], w10 = Wp1[(k + 0) * 128];
        float w01 = Wp0[(k + 1) * 128], w11 = Wp1[(k + 1) * 128];
        float w02 = Wp0[(k + 2) * 128], w12 = Wp1[(k + 2) * 128];
        float w03 = Wp0[(k + 3) * 128], w13 = Wp1[(k + 3) * 128];
        #pragma unroll
        for (int r = 0; r < 8; ++r) {
            float4 xv = *reinterpret_cast<const float4*>(&Xl[rbase + r][k]);
            acc0[r] = fmaf(xv.x, w00, acc0[r]);
            acc1[r] = fmaf(xv.x, w10, acc1[r]);
            acc0[r] = fmaf(xv.y, w01, acc0[r]);
            acc1[r] = fmaf(xv.y, w11, acc1[r]);
            acc0[r] = fmaf(xv.z, w02, acc0[r]);
            acc1[r] = fmaf(xv.z, w12, acc1[r]);
            acc0[r] = fmaf(xv.w, w03, acc0[r]);
            acc1[r] = fmaf(xv.w, w13, acc1[r]);
        }
    }
    #pragma unroll
    for (int r = 0; r < 8; ++r) {
        int gr = row0 + rbase + r;
        if (gr < n) {
            float ns = norm_src[gr];
            out[(size_t)gr * 128 + c0] = f2bf(ns * acc0[r]);
            out[(size_t)gr * 128 + c1] = f2bf(ns * acc1[r]);
        }
    }
}

// Layer 3 mm: X'' = ns*relu(nd*agg2 + b2) at load; y = X''@W3 (fp32, 40 cols).
__global__ __launch_bounds__(256, 4) void mm40_l3_kernel(const float* __restrict__ agg,
        const float* __restrict__ W3, const float* __restrict__ b2,
        const float* __restrict__ norm_dst, const float* __restrict__ norm_src,
        float* __restrict__ y, int n) {
    __shared__ float Xl[32][128];
    int t = threadIdx.x;
    int row0 = blockIdx.x * 32;
    for (int i = t; i < 32 * 32; i += 256) {
        int r = i >> 5, k4 = i & 31;
        int gr = row0 + r;
        float4 xv = make_float4(0.f, 0.f, 0.f, 0.f);
        if (gr < n) {
            xv = reinterpret_cast<const float4*>(agg)[(size_t)gr * 32 + k4];
            float4 bb = reinterpret_cast<const float4*>(b2)[k4];
            float nd = norm_dst[gr], ns = norm_src[gr];
            xv.x = ns * fmaxf(fmaf(nd, xv.x, bb.x), 0.f);
            xv.y = ns * fmaxf(fmaf(nd, xv.y, bb.y), 0.f);
            xv.z = ns * fmaxf(fmaf(nd, xv.z, bb.z), 0.f);
            xv.w = ns * fmaxf(fmaf(nd, xv.w, bb.w), 0.f);
        }
        reinterpret_cast<float4*>(&Xl[r][0])[k4] = xv;
    }
    __syncthreads();
    int wv = t >> 6, lane = t & 63;
    int c = (lane < 40) ? lane : 0;
    float acc[8];
    #pragma unroll
    for (int r = 0; r < 8; ++r) acc[r] = 0.f;
    int rbase = wv * 8;
    const float* Wp = W3 + c;
    for (int k = 0; k < 128; k += 2) {
        float w0 = Wp[(k + 0) * 40];
        float w1 = Wp[(k + 1) * 40];
        #pragma unroll
        for (int r = 0; r < 8; ++r) {
            float2 xv = *reinterpret_cast<const float2*>(&Xl[rbase + r][k]);
            acc[r] = fmaf(xv.x, w0, acc[r]);
            acc[r] = fmaf(xv.y, w1, acc[r]);
        }
    }
    if (lane < 40) {
        #pragma unroll
        for (int r = 0; r < 8; ++r) {
            int gr = row0 + rbase + r;
            if (gr < n) y[(size_t)gr * 40 + lane] = acc[r];
        }
    }
}

// out[v][c] = norm_dst[v] * sum_{u->v} y[u][c] + b3[c], c < 40. One wave/node.
__global__ __launch_bounds__(256) void agg40_kernel(const float* __restrict__ y,
        const int* __restrict__ row_ptr, const int* __restrict__ col,
        const float* __restrict__ norm_dst, const float* __restrict__ b3,
        float* __restrict__ out, int n) {
    int wid  = (blockIdx.x * blockDim.x + threadIdx.x) >> 6;
    int lane = threadIdx.x & 63;
    if (wid >= n) return;
    int start = row_ptr[wid], end = row_ptr[wid + 1];
    float acc = 0.f;
    for (int b = start; b < end; b += 64) {
        int m = end - b; if (m > 64) m = 64;
        int u = 0;
        if (lane < m) u = col[b + lane];
        for (int j = 0; j < m; ++j) {
            int uu = __shfl(u, j);
            if (lane < 40) acc += y[(size_t)uu * 40 + lane];
        }
    }
    if (lane < 40) out[(size_t)wid * 40 + lane] = norm_dst[wid] * acc + b3[lane];
}

extern "C" void kernel_launch(void* const* d_in, const int* in_sizes, int n_in,
                              void* d_out, int out_size, void* d_ws, size_t ws_size,
                              hipStream_t stream) {
    const float* features = (const float*)d_in[0];
    const int*   ei       = (const int*)d_in[1];
    const float* W1 = (const float*)d_in[2];
    const float* b1 = (const float*)d_in[3];
    const float* W2 = (const float*)d_in[4];
    const float* b2 = (const float*)d_in[5];
    const float* W3 = (const float*)d_in[6];
    const float* b3 = (const float*)d_in[7];

    const int n = in_sizes[0] / 128;
    const int E = in_sizes[1] / 2;

    char* w = (char*)d_ws;
    auto alloc = [&](size_t bytes) {
        char* p = w;
        w += (bytes + 255) & ~(size_t)255;
        return p;
    };
    int*    deg      = (int*)   alloc((size_t)2 * n * 4);  // cnt_src | cnt_dst
    float*  norm_src = (float*) alloc((size_t)n * 4);
    float*  norm_dst = (float*) alloc((size_t)n * 4);
    int*    row_ptr  = (int*)   alloc((size_t)(n + 1) * 4);
    int*    partials = (int*)   alloc((size_t)256 * 4);
    int*    tmp_slot = (int*)   alloc((size_t)E * 4);
    int*    col      = (int*)   alloc((size_t)E * 4);
    ushort* xb       = (ushort*)alloc((size_t)n * 128 * 2);  // bf16 table; y aliases this
    float*  bufA     = (float*) alloc((size_t)n * 128 * 4);  // T1 / agg buffer (aliased safely)

    int* deg_out = deg;      // cnt_src
    int* deg_in  = deg + n;  // cnt_dst
    float* T1 = bufA;        // T1 consumed by convert before agg1 overwrites bufA
    float* y  = (float*)xb;  // y (n*40 fp32 = 8MB) aliases xb (12.8MB); xb2 fully
                             // consumed by agg2 before mm40 writes y

    hipMemsetAsync(deg, 0, (size_t)2 * n * 4, stream);

    int eb = (E + 255) / 256;
    int mb = (n + 31) / 32;
    int sb = (n + SCAN_CHUNK - 1) / SCAN_CHUNK;
    int cb = (n * 32 + 255) / 256;
    int ab = (n + 3) / 4;

    mm1_count_kernel<<<mb + eb, 256, 0, stream>>>(features, W1, T1, n, mb,
                                                  ei, E, deg_out, deg_in, tmp_slot);
    scan_blocksum<<<sb, 256, 0, stream>>>(deg_in, n, partials);
    scan_partials<<<1, 256, 0, stream>>>(partials, sb, row_ptr, n);
    scan_emit<<<sb, 256, 0, stream>>>(deg_in, deg_out, partials, n,
                                      row_ptr, norm_src, norm_dst);
    scatter_convert_kernel<<<eb + cb, 256, 0, stream>>>(ei, E, row_ptr, tmp_slot, col, eb,
                                                        T1, norm_src, xb, n);
    agg128_kernel<<<ab, 256, 0, stream>>>(xb, row_ptr, col, bufA, n);
    mm128_l2_kernel<<<mb, 256, 0, stream>>>(bufA, W2, b1, norm_dst, norm_src, xb, n);
    agg128_kernel<<<ab, 256, 0, stream>>>(xb, row_ptr, col, bufA, n);
    mm40_l3_kernel<<<mb, 256, 0, stream>>>(bufA, W3, b2, norm_dst, norm_src, y, n);
    agg40_kernel<<<ab, 256, 0, stream>>>(y, row_ptr, col, norm_dst, b3, (float*)d_out, n);
}